// Round 1
// baseline (1618.130 us; speedup 1.0000x reference)
//
#include <hip/hip_runtime.h>

#define N_NODES 50000
#define N_EDGES 800000
#define IN_F 128
#define OUT_F 32
#define HEADS 4
#define EDGE_F 32
#define HF 128          // HEADS*OUT_F
#define NB 16           // nodes per block in node_kernel
#define EB 64           // edges per block in edge_kernel

__device__ __forceinline__ void atomAddF(float* p, float v) {
    unsafeAtomicAdd(p, v);   // global_atomic_add_f32 on gfx950 (denorm-flush irrelevant here)
}

// ---- fold eW/eb/a_e into w_eff[32x4], b_eff[4] --------------------------
__global__ void prep_kernel(const float* __restrict__ eW, const float* __restrict__ eb,
                            const float* __restrict__ a,
                            float* __restrict__ w_eff, float* __restrict__ b_eff) {
    int t = threadIdx.x;
    if (t < 128) {
        int k = t >> 2, h = t & 3;
        float s = 0.f;
        #pragma unroll
        for (int f = 0; f < EDGE_F; ++f)
            s = fmaf(eW[k * HF + h * OUT_F + f], a[h * 96 + 2 * OUT_F + f], s);
        w_eff[k * 4 + h] = s;
    } else if (t < 132) {
        int h = t - 128;
        float s = 0.f;
        #pragma unroll
        for (int f = 0; f < EDGE_F; ++f)
            s = fmaf(eb[h * OUT_F + f], a[h * 96 + 2 * OUT_F + f], s);
        b_eff[h] = s;
    }
}

// ---- ht = h @ W, alpha_i/alpha_j per node -------------------------------
__global__ __launch_bounds__(128) void node_kernel(
        const float* __restrict__ h, const float* __restrict__ W,
        const float* __restrict__ a,
        float* __restrict__ ht, float* __restrict__ alpha_i, float* __restrict__ alpha_j) {
    int j = threadIdx.x;
    int n0 = blockIdx.x * NB;
    __shared__ __align__(16) float hs[NB][IN_F];
    {   // cooperative float4 load of NB node rows (2048 floats)
        const float4* src = (const float4*)(h + (size_t)n0 * IN_F);
        float4* dst = (float4*)(&hs[0][0]);
        #pragma unroll
        for (int u = 0; u < (NB * IN_F / 4) / 128; ++u)
            dst[j + u * 128] = src[j + u * 128];
    }
    __syncthreads();
    float acc[NB];
    #pragma unroll
    for (int i = 0; i < NB; ++i) acc[i] = 0.f;
    #pragma unroll 4
    for (int k = 0; k < IN_F; ++k) {
        float w = W[k * HF + j];
        #pragma unroll
        for (int i = 0; i < NB; ++i) acc[i] = fmaf(hs[i][k], w, acc[i]);
    }
    int hh = j >> 5, f = j & 31;
    float ai = a[hh * 96 + f];
    float aj = a[hh * 96 + OUT_F + f];
    #pragma unroll
    for (int i = 0; i < NB; ++i) {
        int n = n0 + i;
        ht[(size_t)n * HF + j] = acc[i];
        float pi = acc[i] * ai, pj = acc[i] * aj;
        #pragma unroll
        for (int s = 16; s > 0; s >>= 1) {
            pi += __shfl_down(pi, s, 32);
            pj += __shfl_down(pj, s, 32);
        }
        if (f == 0) { alpha_i[n * 4 + hh] = pi; alpha_j[n * 4 + hh] = pj; }
    }
}

// ---- edge logits -> exp -> denom (atomic) -------------------------------
__global__ __launch_bounds__(256) void edge_kernel(
        const int* __restrict__ row, const int* __restrict__ col,
        const float* __restrict__ ea,
        const float* __restrict__ w_eff, const float* __restrict__ b_eff,
        const float* __restrict__ alpha_i, const float* __restrict__ alpha_j,
        float* __restrict__ att, float* __restrict__ denom) {
    __shared__ __align__(16) float eas[EB][EDGE_F + 4];   // stride 36: 16B-aligned rows, 2-way banks
    __shared__ float ws[128];
    __shared__ float bs[4];
    int t = threadIdx.x;
    int e0 = blockIdx.x * EB;
    if (t < 128) ws[t] = w_eff[t];
    if (t < 4) bs[t] = b_eff[t];
    {   // stage EB edge rows (2048 floats) as float4
        const float4* src = (const float4*)(ea + (size_t)e0 * EDGE_F);
        #pragma unroll
        for (int u = 0; u < 2; ++u) {
            int idx = t + u * 256;
            int i = idx >> 3, f4 = idx & 7;
            ((float4*)&eas[i][0])[f4] = src[idx];
        }
    }
    __syncthreads();
    int i = t >> 2, hh = t & 3;
    int e = e0 + i;
    float s = bs[hh];
    #pragma unroll
    for (int k = 0; k < EDGE_F; ++k) s = fmaf(eas[i][k], ws[k * 4 + hh], s);
    int r = row[e], c = col[e];
    float ev = s + alpha_i[r * 4 + hh] + alpha_j[c * 4 + hh];
    ev = ev > 0.f ? ev : 0.2f * ev;               // leaky_relu(0.2)
    float ex = __expf(ev);                        // no max-shift: |e| <= ~6, fp32-safe
    att[(size_t)e * 4 + hh] = ex;
    atomAddF(&denom[r * 4 + hh], ex);
}

// ---- att normalize (in place in d_out) ----------------------------------
__global__ __launch_bounds__(256) void norm_kernel(
        const int* __restrict__ row, const float* __restrict__ denom,
        float* __restrict__ att) {
    int t = blockIdx.x * 256 + threadIdx.x;       // over E*4
    int e = t >> 2, hh = t & 3;
    int r = row[e];
    att[t] = att[t] / (denom[r * 4 + hh] + 1e-8f);
}

// ---- h_out[row] += att * ht[col]  (scatter, fp32 atomics) ---------------
__global__ __launch_bounds__(256) void agg_kernel(
        const int* __restrict__ row, const int* __restrict__ col,
        const float* __restrict__ att, const float* __restrict__ ht,
        float* __restrict__ hout) {
    size_t t = (size_t)blockIdx.x * 256 + threadIdx.x;   // over E*32 (float4 lanes)
    int e = (int)(t >> 5), q = (int)(t & 31);
    int r = row[e], c = col[e];
    float av = att[(size_t)e * 4 + (q >> 3)];
    float4 hv = ((const float4*)ht)[(size_t)c * 32 + q];
    float* dst = hout + (size_t)r * HF + q * 4;
    atomAddF(dst + 0, av * hv.x);
    atomAddF(dst + 1, av * hv.y);
    atomAddF(dst + 2, av * hv.z);
    atomAddF(dst + 3, av * hv.w);
}

// ---- elu in place -------------------------------------------------------
__global__ __launch_bounds__(256) void elu_kernel(float* __restrict__ hout) {
    int t = blockIdx.x * 256 + threadIdx.x;       // over N*HF
    float v = hout[t];
    hout[t] = v > 0.f ? v : expm1f(v);
}

extern "C" void kernel_launch(void* const* d_in, const int* in_sizes, int n_in,
                              void* d_out, int out_size, void* d_ws, size_t ws_size,
                              hipStream_t stream) {
    const float* h  = (const float*)d_in[0];
    const int*   ei = (const int*)  d_in[1];
    const float* ea = (const float*)d_in[2];
    const float* W  = (const float*)d_in[3];
    const float* a  = (const float*)d_in[4];
    const float* eW = (const float*)d_in[5];
    const float* eb = (const float*)d_in[6];

    float* out  = (float*)d_out;
    float* hout = out;                                   // 50000*128
    float* att  = out + (size_t)N_NODES * HF;            // 800000*4

    float* ws      = (float*)d_ws;
    float* ht      = ws;                                 // 6,400,000 f
    float* alpha_i = ws + (size_t)N_NODES * HF;          // 200,000 f
    float* alpha_j = alpha_i + N_NODES * HEADS;          // 200,000 f
    float* denom   = alpha_j + N_NODES * HEADS;          // 200,000 f
    float* w_eff   = denom   + N_NODES * HEADS;          // 128 f
    float* b_eff   = w_eff + 128;                        // 4 f

    const int* row = ei;
    const int* col = ei + N_EDGES;

    hipMemsetAsync(denom, 0, (size_t)N_NODES * HEADS * sizeof(float), stream);
    hipMemsetAsync(hout, 0, (size_t)N_NODES * HF * sizeof(float), stream);

    prep_kernel<<<1, 160, 0, stream>>>(eW, eb, a, w_eff, b_eff);
    node_kernel<<<N_NODES / NB, 128, 0, stream>>>(h, W, a, ht, alpha_i, alpha_j);
    edge_kernel<<<N_EDGES / EB, 256, 0, stream>>>(row, col, ea, w_eff, b_eff,
                                                  alpha_i, alpha_j, att, denom);
    norm_kernel<<<N_EDGES * HEADS / 256, 256, 0, stream>>>(row, denom, att);
    agg_kernel<<<(int)((size_t)N_EDGES * 32 / 256), 256, 0, stream>>>(row, col, att, ht, hout);
    elu_kernel<<<N_NODES * HF / 256, 256, 0, stream>>>(hout);
}

// Round 2
// 514.225 us; speedup vs baseline: 3.1467x; 3.1467x over previous
//
#include <hip/hip_runtime.h>

#define N_NODES 50000
#define N_EDGES 800000
#define IN_F 128
#define OUT_F 32
#define HEADS 4
#define EDGE_F 32
#define HF 128          // HEADS*OUT_F
#define NB 16           // nodes per block in node_kernel
#define EB 64           // edges per block in edge_kernel

// ---- fold eW/eb/a_e into w_eff[32x4], b_eff[4] --------------------------
__global__ void prep_kernel(const float* __restrict__ eW, const float* __restrict__ eb,
                            const float* __restrict__ a,
                            float* __restrict__ w_eff, float* __restrict__ b_eff) {
    int t = threadIdx.x;
    if (t < 128) {
        int k = t >> 2, h = t & 3;
        float s = 0.f;
        #pragma unroll
        for (int f = 0; f < EDGE_F; ++f)
            s = fmaf(eW[k * HF + h * OUT_F + f], a[h * 96 + 2 * OUT_F + f], s);
        w_eff[k * 4 + h] = s;
    } else if (t < 132) {
        int h = t - 128;
        float s = 0.f;
        #pragma unroll
        for (int f = 0; f < EDGE_F; ++f)
            s = fmaf(eb[h * OUT_F + f], a[h * 96 + 2 * OUT_F + f], s);
        b_eff[h] = s;
    }
}

// ---- ht = h @ W, alpha_i/alpha_j per node -------------------------------
__global__ __launch_bounds__(128) void node_kernel(
        const float* __restrict__ h, const float* __restrict__ W,
        const float* __restrict__ a,
        float* __restrict__ ht, float* __restrict__ alpha_i, float* __restrict__ alpha_j) {
    int j = threadIdx.x;
    int n0 = blockIdx.x * NB;
    __shared__ __align__(16) float hs[NB][IN_F];
    {   // cooperative float4 load of NB node rows (2048 floats)
        const float4* src = (const float4*)(h + (size_t)n0 * IN_F);
        float4* dst = (float4*)(&hs[0][0]);
        #pragma unroll
        for (int u = 0; u < (NB * IN_F / 4) / 128; ++u)
            dst[j + u * 128] = src[j + u * 128];
    }
    __syncthreads();
    float acc[NB];
    #pragma unroll
    for (int i = 0; i < NB; ++i) acc[i] = 0.f;
    #pragma unroll 4
    for (int k = 0; k < IN_F; ++k) {
        float w = W[k * HF + j];
        #pragma unroll
        for (int i = 0; i < NB; ++i) acc[i] = fmaf(hs[i][k], w, acc[i]);
    }
    int hh = j >> 5, f = j & 31;
    float ai = a[hh * 96 + f];
    float aj = a[hh * 96 + OUT_F + f];
    #pragma unroll
    for (int i = 0; i < NB; ++i) {
        int n = n0 + i;
        ht[(size_t)n * HF + j] = acc[i];
        float pi = acc[i] * ai, pj = acc[i] * aj;
        #pragma unroll
        for (int s = 16; s > 0; s >>= 1) {
            pi += __shfl_down(pi, s, 32);
            pj += __shfl_down(pj, s, 32);
        }
        if (f == 0) { alpha_i[n * 4 + hh] = pi; alpha_j[n * 4 + hh] = pj; }
    }
}

// ---- CSR build: degree histogram ---------------------------------------
__global__ __launch_bounds__(256) void count_kernel(const int* __restrict__ row,
                                                    int* __restrict__ deg) {
    int e = blockIdx.x * 256 + threadIdx.x;
    if (e < N_EDGES) atomicAdd(&deg[row[e]], 1);
}

// ---- CSR build: exclusive scan over 50000 degrees (single block) --------
#define SCAN_T 256
#define SCAN_CH ((N_NODES + SCAN_T - 1) / SCAN_T)   // 196
__global__ __launch_bounds__(SCAN_T) void scan_kernel(const int* __restrict__ deg,
                                                      int* __restrict__ row_off,
                                                      int* __restrict__ cursor) {
    __shared__ int sums[SCAN_T];
    int t = threadIdx.x;
    int s0 = t * SCAN_CH, s1 = min(s0 + SCAN_CH, N_NODES);
    int s = 0;
    for (int i = s0; i < s1; ++i) s += deg[i];
    sums[t] = s;
    __syncthreads();
    for (int off = 1; off < SCAN_T; off <<= 1) {      // Hillis–Steele inclusive
        int u = (t >= off) ? sums[t - off] : 0;
        __syncthreads();
        sums[t] += u;
        __syncthreads();
    }
    int base = sums[t] - s;                           // exclusive prefix
    for (int i = s0; i < s1; ++i) {
        row_off[i] = base; cursor[i] = base;
        base += deg[i];
    }
    if (t == SCAN_T - 1) row_off[N_NODES] = base;
}

// ---- edge logits -> raw exp (orig order) + CSR scatter ------------------
__global__ __launch_bounds__(256) void edge_kernel(
        const int* __restrict__ row, const int* __restrict__ col,
        const float* __restrict__ ea,
        const float* __restrict__ w_eff, const float* __restrict__ b_eff,
        const float* __restrict__ alpha_i, const float* __restrict__ alpha_j,
        float* __restrict__ att, int* __restrict__ cursor,
        int* __restrict__ csr_col, int* __restrict__ csr_eid) {
    __shared__ __align__(16) float eas[EB][EDGE_F + 4];
    __shared__ float wsd[128];
    __shared__ float bs[4];
    int t = threadIdx.x;
    int e0 = blockIdx.x * EB;
    if (t < 128) wsd[t] = w_eff[t];
    if (t < 4) bs[t] = b_eff[t];
    {   // stage EB edge rows (2048 floats) as float4
        const float4* src = (const float4*)(ea + (size_t)e0 * EDGE_F);
        #pragma unroll
        for (int u = 0; u < 2; ++u) {
            int idx = t + u * 256;
            int i = idx >> 3, f4 = idx & 7;
            ((float4*)&eas[i][0])[f4] = src[idx];
        }
    }
    __syncthreads();
    int i = t >> 2, hh = t & 3;
    int e = e0 + i;
    float s = bs[hh];
    #pragma unroll
    for (int k = 0; k < EDGE_F; ++k) s = fmaf(eas[i][k], wsd[k * 4 + hh], s);
    int r = row[e], c = col[e];
    float ev = s + alpha_i[r * 4 + hh] + alpha_j[c * 4 + hh];
    ev = ev > 0.f ? ev : 0.2f * ev;               // leaky_relu(0.2)
    float ex = __expf(ev);                        // no max-shift: |e| small, fp32-safe
    att[(size_t)e * 4 + hh] = ex;                 // RAW ex; normalized later by agg
    int pos = 0;
    if (hh == 0) pos = atomicAdd(&cursor[r], 1);
    pos = __shfl(pos, (t & 63) & ~3, 64);         // broadcast within the 4-lane group
    if (hh == 0) { csr_col[pos] = c; csr_eid[pos] = e; }
}

// ---- per-node aggregation: one wave per node ----------------------------
// h_out[n] = elu( (sum_e ex_e * ht[col_e]) / (den + 1e-8) ), att[eid] = ex/den
__global__ __launch_bounds__(256) void agg_kernel(
        const int* __restrict__ row_off, const int* __restrict__ csr_col,
        const int* __restrict__ csr_eid, const float* __restrict__ ht,
        float* __restrict__ hout, float* __restrict__ att) {
    int wave = threadIdx.x >> 6;
    int lane = threadIdx.x & 63;
    int n = blockIdx.x * 4 + wave;
    if (n >= N_NODES) return;
    int beg = row_off[n], end = row_off[n + 1];
    int head2 = lane >> 4;                         // head of this lane's float2 (2*lane..2*lane+1)
    float2 acc0 = {0.f, 0.f}, acc1 = {0.f, 0.f};
    float den0 = 0.f, den1 = 0.f;
    int p = beg;
    for (; p + 1 < end; p += 2) {                  // unroll x2 for load ILP
        int cA = csr_col[p],     eA = csr_eid[p];
        int cB = csr_col[p + 1], eB = csr_eid[p + 1];
        float exA = att[(size_t)eA * 4 + head2];
        float exB = att[(size_t)eB * 4 + head2];
        float2 hvA = ((const float2*)(ht + (size_t)cA * HF))[lane];
        float2 hvB = ((const float2*)(ht + (size_t)cB * HF))[lane];
        acc0.x = fmaf(exA, hvA.x, acc0.x); acc0.y = fmaf(exA, hvA.y, acc0.y);
        acc1.x = fmaf(exB, hvB.x, acc1.x); acc1.y = fmaf(exB, hvB.y, acc1.y);
        den0 += exA; den1 += exB;
    }
    if (p < end) {
        int cA = csr_col[p], eA = csr_eid[p];
        float exA = att[(size_t)eA * 4 + head2];
        float2 hvA = ((const float2*)(ht + (size_t)cA * HF))[lane];
        acc0.x = fmaf(exA, hvA.x, acc0.x); acc0.y = fmaf(exA, hvA.y, acc0.y);
        den0 += exA;
    }
    float den = den0 + den1;
    float rden = 1.0f / (den + 1e-8f);
    float ox = (acc0.x + acc1.x) * rden, oy = (acc0.y + acc1.y) * rden;
    ox = ox > 0.f ? ox : expm1f(ox);               // fused ELU
    oy = oy > 0.f ? oy : expm1f(oy);
    float2 o = {ox, oy};
    ((float2*)(hout + (size_t)n * HF))[lane] = o;
    // normalize att in place: 16 edges per iteration (4 lanes per edge)
    int h = lane & 3;
    float rden_h = __shfl(rden, h * 16, 64);       // lanes h*16.. hold head-h rden
    for (int p0 = beg; p0 < end; p0 += 16) {
        int q = p0 + (lane >> 2);
        if (q < end) {
            int eid = csr_eid[q];
            float ex = att[(size_t)eid * 4 + h];
            att[(size_t)eid * 4 + h] = ex * rden_h;
        }
    }
}

extern "C" void kernel_launch(void* const* d_in, const int* in_sizes, int n_in,
                              void* d_out, int out_size, void* d_ws, size_t ws_size,
                              hipStream_t stream) {
    const float* h  = (const float*)d_in[0];
    const int*   ei = (const int*)  d_in[1];
    const float* ea = (const float*)d_in[2];
    const float* W  = (const float*)d_in[3];
    const float* a  = (const float*)d_in[4];
    const float* eW = (const float*)d_in[5];
    const float* eb = (const float*)d_in[6];

    float* out  = (float*)d_out;
    float* hout = out;                                   // 50000*128
    float* att  = out + (size_t)N_NODES * HF;            // 800000*4 (raw ex, then normalized)

    float* wsf     = (float*)d_ws;
    float* ht      = wsf;                                // 6,400,000 f
    float* alpha_i = ht + (size_t)N_NODES * HF;          // 200,000 f
    float* alpha_j = alpha_i + N_NODES * HEADS;          // 200,000 f
    float* w_eff   = alpha_j + N_NODES * HEADS;          // 128 f
    float* b_eff   = w_eff + 128;                        // 4 f
    int*   deg     = (int*)(b_eff + 4);                  // 50,000 i
    int*   row_off = deg + N_NODES;                      // 50,001 i
    int*   cursor  = row_off + N_NODES + 1;              // 50,000 i
    int*   csr_col = cursor + N_NODES;                   // 800,000 i
    int*   csr_eid = csr_col + N_EDGES;                  // 800,000 i

    const int* row = ei;
    const int* col = ei + N_EDGES;

    hipMemsetAsync(deg, 0, (size_t)N_NODES * sizeof(int), stream);

    prep_kernel<<<1, 160, 0, stream>>>(eW, eb, a, w_eff, b_eff);
    node_kernel<<<N_NODES / NB, 128, 0, stream>>>(h, W, a, ht, alpha_i, alpha_j);
    count_kernel<<<(N_EDGES + 255) / 256, 256, 0, stream>>>(row, deg);
    scan_kernel<<<1, SCAN_T, 0, stream>>>(deg, row_off, cursor);
    edge_kernel<<<N_EDGES / EB, 256, 0, stream>>>(row, col, ea, w_eff, b_eff,
                                                  alpha_i, alpha_j, att,
                                                  cursor, csr_col, csr_eid);
    agg_kernel<<<(N_NODES + 3) / 4, 256, 0, stream>>>(row_off, csr_col, csr_eid,
                                                      ht, hout, att);
}

// Round 3
// 402.447 us; speedup vs baseline: 4.0207x; 1.2777x over previous
//
#include <hip/hip_runtime.h>

#define N_NODES 50000
#define N_EDGES 800000
#define IN_F 128
#define OUT_F 32
#define HEADS 4
#define EDGE_F 32
#define HF 128          // HEADS*OUT_F
#define NB 16           // nodes per block in node_kernel
#define EB 64           // edges per block in edge_kernel
#define SB 256          // scan block size
#define NBLK ((N_NODES + SB - 1) / SB)   // 196 scan blocks

// ---- fold eW/eb/a_e into w_eff[32x4], b_eff[4] --------------------------
__global__ void prep_kernel(const float* __restrict__ eW, const float* __restrict__ eb,
                            const float* __restrict__ a,
                            float* __restrict__ w_eff, float* __restrict__ b_eff) {
    int t = threadIdx.x;
    if (t < 128) {
        int k = t >> 2, h = t & 3;
        float s = 0.f;
        #pragma unroll
        for (int f = 0; f < EDGE_F; ++f)
            s = fmaf(eW[k * HF + h * OUT_F + f], a[h * 96 + 2 * OUT_F + f], s);
        w_eff[k * 4 + h] = s;
    } else if (t < 132) {
        int h = t - 128;
        float s = 0.f;
        #pragma unroll
        for (int f = 0; f < EDGE_F; ++f)
            s = fmaf(eb[h * OUT_F + f], a[h * 96 + 2 * OUT_F + f], s);
        b_eff[h] = s;
    }
}

// ---- ht = h @ W, alpha_i/alpha_j per node -------------------------------
__global__ __launch_bounds__(128) void node_kernel(
        const float* __restrict__ h, const float* __restrict__ W,
        const float* __restrict__ a,
        float* __restrict__ ht, float* __restrict__ alpha_i, float* __restrict__ alpha_j) {
    int j = threadIdx.x;
    int n0 = blockIdx.x * NB;
    __shared__ __align__(16) float hs[NB][IN_F];
    {   // cooperative float4 load of NB node rows (2048 floats)
        const float4* src = (const float4*)(h + (size_t)n0 * IN_F);
        float4* dst = (float4*)(&hs[0][0]);
        #pragma unroll
        for (int u = 0; u < (NB * IN_F / 4) / 128; ++u)
            dst[j + u * 128] = src[j + u * 128];
    }
    __syncthreads();
    float acc[NB];
    #pragma unroll
    for (int i = 0; i < NB; ++i) acc[i] = 0.f;
    #pragma unroll 4
    for (int k = 0; k < IN_F; ++k) {
        float w = W[k * HF + j];
        #pragma unroll
        for (int i = 0; i < NB; ++i) acc[i] = fmaf(hs[i][k], w, acc[i]);
    }
    int hh = j >> 5, f = j & 31;
    float ai = a[hh * 96 + f];
    float aj = a[hh * 96 + OUT_F + f];
    #pragma unroll
    for (int i = 0; i < NB; ++i) {
        int n = n0 + i;
        ht[(size_t)n * HF + j] = acc[i];
        float pi = acc[i] * ai, pj = acc[i] * aj;
        #pragma unroll
        for (int s = 16; s > 0; s >>= 1) {
            pi += __shfl_down(pi, s, 32);
            pj += __shfl_down(pj, s, 32);
        }
        if (f == 0) { alpha_i[n * 4 + hh] = pi; alpha_j[n * 4 + hh] = pj; }
    }
}

// ---- CSR build: degree histogram ---------------------------------------
__global__ __launch_bounds__(256) void count_kernel(const int* __restrict__ row,
                                                    int* __restrict__ deg) {
    int e = blockIdx.x * 256 + threadIdx.x;
    if (e < N_EDGES) atomicAdd(&deg[row[e]], 1);
}

// ---- hierarchical exclusive scan ----------------------------------------
__device__ __forceinline__ int block_incl_scan(int v, int lane, int wid, int* wsum) {
    int x = v;
    #pragma unroll
    for (int s = 1; s < 64; s <<= 1) {
        int y = __shfl_up(x, s, 64);
        if (lane >= s) x += y;
    }
    if (lane == 63) wsum[wid] = x;
    __syncthreads();
    int add = 0;
    #pragma unroll
    for (int w = 0; w < 4; ++w) add += (w < wid) ? wsum[w] : 0;
    return x + add;            // block-level inclusive scan of v
}

__global__ __launch_bounds__(SB) void scan1_kernel(const int* __restrict__ deg,
                                                   int* __restrict__ row_off,
                                                   int* __restrict__ blk_sums) {
    __shared__ int wsum[4];
    int i = blockIdx.x * SB + threadIdx.x;
    int v = (i < N_NODES) ? deg[i] : 0;
    int incl = block_incl_scan(v, threadIdx.x & 63, threadIdx.x >> 6, wsum);
    if (i < N_NODES) row_off[i] = incl - v;              // local exclusive
    if (threadIdx.x == SB - 1) blk_sums[blockIdx.x] = incl;
}

__global__ __launch_bounds__(SB) void scan2_kernel(int* __restrict__ blk_sums,
                                                   int* __restrict__ blk_off,
                                                   int* __restrict__ row_off) {
    __shared__ int wsum[4];
    int t = threadIdx.x;
    int v = (t < NBLK) ? blk_sums[t] : 0;
    int incl = block_incl_scan(v, t & 63, t >> 6, wsum);
    if (t < NBLK) blk_off[t] = incl - v;                 // exclusive block offset
    if (t == SB - 1) row_off[N_NODES] = incl;            // grand total (== N_EDGES)
}

__global__ __launch_bounds__(SB) void scan3_kernel(const int* __restrict__ blk_off,
                                                   int* __restrict__ row_off,
                                                   int* __restrict__ cursor) {
    int i = blockIdx.x * SB + threadIdx.x;
    if (i < N_NODES) {
        int v = row_off[i] + blk_off[blockIdx.x];
        row_off[i] = v;
        cursor[i] = v;
    }
}

// ---- edge logits -> raw exp (orig order) + CSR scatter ------------------
__global__ __launch_bounds__(256) void edge_kernel(
        const int* __restrict__ row, const int* __restrict__ col,
        const float* __restrict__ ea,
        const float* __restrict__ w_eff, const float* __restrict__ b_eff,
        const float* __restrict__ alpha_i, const float* __restrict__ alpha_j,
        float* __restrict__ att, int* __restrict__ cursor,
        int* __restrict__ csr_col, int* __restrict__ csr_eid) {
    __shared__ __align__(16) float eas[EB][EDGE_F + 4];
    __shared__ float wsd[128];
    __shared__ float bs[4];
    int t = threadIdx.x;
    int e0 = blockIdx.x * EB;
    if (t < 128) wsd[t] = w_eff[t];
    if (t < 4) bs[t] = b_eff[t];
    {   // stage EB edge rows (2048 floats) as float4
        const float4* src = (const float4*)(ea + (size_t)e0 * EDGE_F);
        #pragma unroll
        for (int u = 0; u < 2; ++u) {
            int idx = t + u * 256;
            int i = idx >> 3, f4 = idx & 7;
            ((float4*)&eas[i][0])[f4] = src[idx];
        }
    }
    __syncthreads();
    int i = t >> 2, hh = t & 3;
    int e = e0 + i;
    float s = bs[hh];
    #pragma unroll
    for (int k = 0; k < EDGE_F; ++k) s = fmaf(eas[i][k], wsd[k * 4 + hh], s);
    int r = row[e], c = col[e];
    float ev = s + alpha_i[r * 4 + hh] + alpha_j[c * 4 + hh];
    ev = ev > 0.f ? ev : 0.2f * ev;               // leaky_relu(0.2)
    float ex = __expf(ev);                        // no max-shift: |e| small, fp32-safe
    att[(size_t)e * 4 + hh] = ex;                 // RAW ex; normalized later by agg
    int pos = 0;
    if (hh == 0) pos = atomicAdd(&cursor[r], 1);
    pos = __shfl(pos, (t & 63) & ~3, 64);         // broadcast within the 4-lane group
    if (hh == 0) { csr_col[pos] = c; csr_eid[pos] = e; }
}

// ---- per-node aggregation: one wave per node ----------------------------
// h_out[n] = elu( (sum_e ex_e * ht[col_e]) / (den + 1e-8) ), att[eid] = ex/den
__global__ __launch_bounds__(256) void agg_kernel(
        const int* __restrict__ row_off, const int* __restrict__ csr_col,
        const int* __restrict__ csr_eid, const float* __restrict__ ht,
        float* __restrict__ hout, float* __restrict__ att) {
    int wave = threadIdx.x >> 6;
    int lane = threadIdx.x & 63;
    int n = blockIdx.x * 4 + wave;
    if (n >= N_NODES) return;
    int beg = row_off[n], end = row_off[n + 1];
    int head2 = lane >> 4;                         // head of this lane's float2
    float2 acc0 = {0.f, 0.f}, acc1 = {0.f, 0.f};
    float den0 = 0.f, den1 = 0.f;
    int p = beg;
    for (; p + 1 < end; p += 2) {                  // unroll x2 for load ILP
        int cA = csr_col[p],     eA = csr_eid[p];
        int cB = csr_col[p + 1], eB = csr_eid[p + 1];
        float exA = att[(size_t)eA * 4 + head2];
        float exB = att[(size_t)eB * 4 + head2];
        float2 hvA = ((const float2*)(ht + (size_t)cA * HF))[lane];
        float2 hvB = ((const float2*)(ht + (size_t)cB * HF))[lane];
        acc0.x = fmaf(exA, hvA.x, acc0.x); acc0.y = fmaf(exA, hvA.y, acc0.y);
        acc1.x = fmaf(exB, hvB.x, acc1.x); acc1.y = fmaf(exB, hvB.y, acc1.y);
        den0 += exA; den1 += exB;
    }
    if (p < end) {
        int cA = csr_col[p], eA = csr_eid[p];
        float exA = att[(size_t)eA * 4 + head2];
        float2 hvA = ((const float2*)(ht + (size_t)cA * HF))[lane];
        acc0.x = fmaf(exA, hvA.x, acc0.x); acc0.y = fmaf(exA, hvA.y, acc0.y);
        den0 += exA;
    }
    float den = den0 + den1;
    float rden = 1.0f / (den + 1e-8f);
    float ox = (acc0.x + acc1.x) * rden, oy = (acc0.y + acc1.y) * rden;
    ox = ox > 0.f ? ox : expm1f(ox);               // fused ELU
    oy = oy > 0.f ? oy : expm1f(oy);
    float2 o = {ox, oy};
    ((float2*)(hout + (size_t)n * HF))[lane] = o;
    // normalize att in place: 16 edges per iteration (4 lanes per edge)
    int h = lane & 3;
    float rden_h = __shfl(rden, h * 16, 64);       // lanes h*16.. hold head-h rden
    for (int p0 = beg; p0 < end; p0 += 16) {
        int q = p0 + (lane >> 2);
        if (q < end) {
            int eid = csr_eid[q];
            float ex = att[(size_t)eid * 4 + h];
            att[(size_t)eid * 4 + h] = ex * rden_h;
        }
    }
}

extern "C" void kernel_launch(void* const* d_in, const int* in_sizes, int n_in,
                              void* d_out, int out_size, void* d_ws, size_t ws_size,
                              hipStream_t stream) {
    const float* h  = (const float*)d_in[0];
    const int*   ei = (const int*)  d_in[1];
    const float* ea = (const float*)d_in[2];
    const float* W  = (const float*)d_in[3];
    const float* a  = (const float*)d_in[4];
    const float* eW = (const float*)d_in[5];
    const float* eb = (const float*)d_in[6];

    float* out  = (float*)d_out;
    float* hout = out;                                   // 50000*128
    float* att  = out + (size_t)N_NODES * HF;            // 800000*4 (raw ex, then normalized)

    float* wsf     = (float*)d_ws;
    float* ht      = wsf;                                // 6,400,000 f
    float* alpha_i = ht + (size_t)N_NODES * HF;          // 200,000 f
    float* alpha_j = alpha_i + N_NODES * HEADS;          // 200,000 f
    float* w_eff   = alpha_j + N_NODES * HEADS;          // 128 f
    float* b_eff   = w_eff + 128;                        // 4 f
    int*   deg     = (int*)(b_eff + 4);                  // 50,000 i
    int*   row_off = deg + N_NODES;                      // 50,001 i
    int*   cursor  = row_off + N_NODES + 1;              // 50,000 i
    int*   csr_col = cursor + N_NODES;                   // 800,000 i
    int*   csr_eid = csr_col + N_EDGES;                  // 800,000 i
    int*   blk_sums= csr_eid + N_EDGES;                  // 196 i
    int*   blk_off = blk_sums + NBLK;                    // 196 i

    const int* row = ei;
    const int* col = ei + N_EDGES;

    hipMemsetAsync(deg, 0, (size_t)N_NODES * sizeof(int), stream);

    prep_kernel<<<1, 160, 0, stream>>>(eW, eb, a, w_eff, b_eff);
    node_kernel<<<N_NODES / NB, 128, 0, stream>>>(h, W, a, ht, alpha_i, alpha_j);
    count_kernel<<<(N_EDGES + 255) / 256, 256, 0, stream>>>(row, deg);
    scan1_kernel<<<NBLK, SB, 0, stream>>>(deg, row_off, blk_sums);
    scan2_kernel<<<1, SB, 0, stream>>>(blk_sums, blk_off, row_off);
    scan3_kernel<<<NBLK, SB, 0, stream>>>(blk_off, row_off, cursor);
    edge_kernel<<<N_EDGES / EB, 256, 0, stream>>>(row, col, ea, w_eff, b_eff,
                                                  alpha_i, alpha_j, att,
                                                  cursor, csr_col, csr_eid);
    agg_kernel<<<(N_NODES + 3) / 4, 256, 0, stream>>>(row_off, csr_col, csr_eid,
                                                      ht, hout, att);
}

// Round 5
// 389.696 us; speedup vs baseline: 4.1523x; 1.0327x over previous
//
#include <hip/hip_runtime.h>
#include <hip/hip_bf16.h>

#define N_NODES 50000
#define N_EDGES 800000
#define IN_F 128
#define OUT_F 32
#define HEADS 4
#define EDGE_F 32
#define HF 128          // HEADS*OUT_F
#define NB 16           // nodes per block in node_kernel (50000 = 3125*16 exact)
#define EB 64           // edges per block in edge_kernel
#define SB 256          // scan block size
#define NBLK ((N_NODES + SB - 1) / SB)   // 196 scan blocks

// ---- fold eW/eb/a_e into w_eff[32x4], b_eff[4] --------------------------
__global__ void prep_kernel(const float* __restrict__ eW, const float* __restrict__ eb,
                            const float* __restrict__ a,
                            float* __restrict__ w_eff, float* __restrict__ b_eff) {
    int t = threadIdx.x;
    if (t < 128) {
        int k = t >> 2, h = t & 3;
        float s = 0.f;
        #pragma unroll
        for (int f = 0; f < EDGE_F; ++f)
            s = fmaf(eW[k * HF + h * OUT_F + f], a[h * 96 + 2 * OUT_F + f], s);
        w_eff[k * 4 + h] = s;
    } else if (t < 132) {
        int h = t - 128;
        float s = 0.f;
        #pragma unroll
        for (int f = 0; f < EDGE_F; ++f)
            s = fmaf(eb[h * OUT_F + f], a[h * 96 + 2 * OUT_F + f], s);
        b_eff[h] = s;
    }
}

// ---- ht = h @ W (fp32 math, bf16 out), alpha_i/alpha_j per node ---------
// 256 threads: wave g handles nodes n0+4g..n0+4g+3; lane owns cols 2L,2L+1.
__global__ __launch_bounds__(256) void node_kernel(
        const float* __restrict__ h, const float* __restrict__ W,
        const float* __restrict__ a,
        __hip_bfloat16* __restrict__ ht_bf,
        float* __restrict__ alpha_i, float* __restrict__ alpha_j) {
    int tid = threadIdx.x;
    int g = tid >> 6, lane = tid & 63;
    int n0 = blockIdx.x * NB;
    __shared__ __align__(16) float hs[NB][IN_F];
    {   // cooperative float4 load of 16 node rows (2048 floats)
        const float4* src = (const float4*)(h + (size_t)n0 * IN_F);
        float4* dst = (float4*)(&hs[0][0]);
        dst[tid] = src[tid];
        dst[tid + 256] = src[tid + 256];
    }
    __syncthreads();
    float acc0[4] = {0.f, 0.f, 0.f, 0.f};
    float acc1[4] = {0.f, 0.f, 0.f, 0.f};
    const float2* Wv = (const float2*)W;       // row k: float2 idx k*64 + lane
    #pragma unroll 8
    for (int k4 = 0; k4 < IN_F / 4; ++k4) {
        float4 hv[4];
        #pragma unroll
        for (int i = 0; i < 4; ++i)
            hv[i] = *(const float4*)&hs[g * 4 + i][k4 * 4];
        #pragma unroll
        for (int kk = 0; kk < 4; ++kk) {
            float2 w = Wv[(k4 * 4 + kk) * 64 + lane];
            #pragma unroll
            for (int i = 0; i < 4; ++i) {
                float hvv = (&hv[i].x)[kk];
                acc0[i] = fmaf(hvv, w.x, acc0[i]);
                acc1[i] = fmaf(hvv, w.y, acc1[i]);
            }
        }
    }
    int hh = lane >> 4;                        // head of cols 2L,2L+1
    int f0 = (2 * lane) & 31;
    float ai0 = a[hh * 96 + f0],      ai1 = a[hh * 96 + f0 + 1];
    float aj0 = a[hh * 96 + 32 + f0], aj1 = a[hh * 96 + 32 + f0 + 1];
    #pragma unroll
    for (int i = 0; i < 4; ++i) {
        int n = n0 + g * 4 + i;
        *(__hip_bfloat162*)(ht_bf + (size_t)n * HF + 2 * lane) =
            __float22bfloat162_rn(make_float2(acc0[i], acc1[i]));
        float pi = fmaf(acc0[i], ai0, acc1[i] * ai1);
        float pj = fmaf(acc0[i], aj0, acc1[i] * aj1);
        #pragma unroll
        for (int s = 8; s > 0; s >>= 1) {      // reduce within 16-lane head segment
            pi += __shfl_down(pi, s, 16);
            pj += __shfl_down(pj, s, 16);
        }
        if ((lane & 15) == 0) {
            alpha_i[n * 4 + hh] = pi;
            alpha_j[n * 4 + hh] = pj;
        }
    }
}

// ---- CSR build: degree histogram (int4 loads) ---------------------------
__global__ __launch_bounds__(256) void count_kernel(const int* __restrict__ row,
                                                    int* __restrict__ deg) {
    int t = blockIdx.x * 256 + threadIdx.x;        // over N_EDGES/4 = 200000
    if (t < N_EDGES / 4) {                         // FIX: 782 blocks, guard tail
        int4 r4 = ((const int4*)row)[t];
        atomicAdd(&deg[r4.x], 1);
        atomicAdd(&deg[r4.y], 1);
        atomicAdd(&deg[r4.z], 1);
        atomicAdd(&deg[r4.w], 1);
    }
}

// ---- hierarchical exclusive scan ----------------------------------------
__device__ __forceinline__ int block_incl_scan(int v, int lane, int wid, int* wsum) {
    int x = v;
    #pragma unroll
    for (int s = 1; s < 64; s <<= 1) {
        int y = __shfl_up(x, s, 64);
        if (lane >= s) x += y;
    }
    if (lane == 63) wsum[wid] = x;
    __syncthreads();
    int add = 0;
    #pragma unroll
    for (int w = 0; w < 4; ++w) add += (w < wid) ? wsum[w] : 0;
    return x + add;            // block-level inclusive scan of v
}

__global__ __launch_bounds__(SB) void scan1_kernel(const int* __restrict__ deg,
                                                   int* __restrict__ row_off,
                                                   int* __restrict__ blk_sums) {
    __shared__ int wsum[4];
    int i = blockIdx.x * SB + threadIdx.x;
    int v = (i < N_NODES) ? deg[i] : 0;
    int incl = block_incl_scan(v, threadIdx.x & 63, threadIdx.x >> 6, wsum);
    if (i < N_NODES) row_off[i] = incl - v;              // local exclusive
    if (threadIdx.x == SB - 1) blk_sums[blockIdx.x] = incl;
}

__global__ __launch_bounds__(SB) void scan2_kernel(int* __restrict__ blk_sums,
                                                   int* __restrict__ blk_off,
                                                   int* __restrict__ row_off) {
    __shared__ int wsum[4];
    int t = threadIdx.x;
    int v = (t < NBLK) ? blk_sums[t] : 0;
    int incl = block_incl_scan(v, t & 63, t >> 6, wsum);
    if (t < NBLK) blk_off[t] = incl - v;                 // exclusive block offset
    if (t == SB - 1) row_off[N_NODES] = incl;            // grand total (== N_EDGES)
}

__global__ __launch_bounds__(SB) void scan3_kernel(const int* __restrict__ blk_off,
                                                   int* __restrict__ row_off,
                                                   int* __restrict__ cursor) {
    int i = blockIdx.x * SB + threadIdx.x;
    if (i < N_NODES) {
        int v = row_off[i] + blk_off[blockIdx.x];
        row_off[i] = v;
        cursor[i] = v;
    }
}

// ---- edge logits -> exp scattered into CSR order ------------------------
__global__ __launch_bounds__(256) void edge_kernel(
        const int* __restrict__ row, const int* __restrict__ col,
        const float* __restrict__ ea,
        const float* __restrict__ w_eff, const float* __restrict__ b_eff,
        const float* __restrict__ alpha_i, const float* __restrict__ alpha_j,
        int* __restrict__ cursor, int2* __restrict__ csr,
        float* __restrict__ exs) {
    __shared__ __align__(16) float eas[EB][EDGE_F + 4];
    __shared__ float wsd[128];
    __shared__ float bs[4];
    int t = threadIdx.x;
    int e0 = blockIdx.x * EB;
    if (t < 128) wsd[t] = w_eff[t];
    if (t < 4) bs[t] = b_eff[t];
    {   // stage EB edge rows (2048 floats) as float4
        const float4* src = (const float4*)(ea + (size_t)e0 * EDGE_F);
        #pragma unroll
        for (int u = 0; u < 2; ++u) {
            int idx = t + u * 256;
            int i = idx >> 3, f4 = idx & 7;
            ((float4*)&eas[i][0])[f4] = src[idx];
        }
    }
    __syncthreads();
    int i = t >> 2, hh = t & 3;
    int e = e0 + i;
    float s = bs[hh];
    #pragma unroll
    for (int k = 0; k < EDGE_F; ++k) s = fmaf(eas[i][k], wsd[k * 4 + hh], s);
    int r = row[e], c = col[e];
    float ev = s + alpha_i[r * 4 + hh] + alpha_j[c * 4 + hh];
    ev = ev > 0.f ? ev : 0.2f * ev;               // leaky_relu(0.2)
    float ex = __expf(ev);                        // no max-shift: |e| small, fp32-safe
    int pos = 0;
    if (hh == 0) pos = atomicAdd(&cursor[r], 1);
    pos = __shfl(pos, (t & 63) & ~3, 64);         // broadcast within the 4-lane group
    if (hh == 0) csr[pos] = make_int2(c, e);
    exs[(size_t)pos * 4 + hh] = ex;               // CSR-ordered raw exp
}

// ---- per-node aggregation: one wave per node ----------------------------
// h_out[n] = elu( (sum ex * ht_bf[col]) / (den+1e-8) ); att[eid] = ex/den
__global__ __launch_bounds__(256) void agg_kernel(
        const int* __restrict__ row_off, const int2* __restrict__ csr,
        const float* __restrict__ exs, const __hip_bfloat16* __restrict__ ht_bf,
        float* __restrict__ hout, float* __restrict__ att) {
    int wave = threadIdx.x >> 6;
    int lane = threadIdx.x & 63;
    int n = blockIdx.x * 4 + wave;
    if (n >= N_NODES) return;
    int beg = row_off[n], end = row_off[n + 1];
    int h2 = lane >> 4;                            // head of cols 2L,2L+1
    float2 acc0 = {0.f, 0.f}, acc1 = {0.f, 0.f};
    float den0 = 0.f, den1 = 0.f;
    int p = beg;
    for (; p + 1 < end; p += 2) {                  // unroll x2 for load ILP
        int2 ceA = csr[p], ceB = csr[p + 1];
        float exA = exs[(size_t)p * 4 + h2];
        float exB = exs[(size_t)(p + 1) * 4 + h2];
        float2 hvA = __bfloat1622float2(
            *(const __hip_bfloat162*)(ht_bf + (size_t)ceA.x * HF + 2 * lane));
        float2 hvB = __bfloat1622float2(
            *(const __hip_bfloat162*)(ht_bf + (size_t)ceB.x * HF + 2 * lane));
        acc0.x = fmaf(exA, hvA.x, acc0.x); acc0.y = fmaf(exA, hvA.y, acc0.y);
        acc1.x = fmaf(exB, hvB.x, acc1.x); acc1.y = fmaf(exB, hvB.y, acc1.y);
        den0 += exA; den1 += exB;
    }
    if (p < end) {
        int2 ceA = csr[p];
        float exA = exs[(size_t)p * 4 + h2];
        float2 hvA = __bfloat1622float2(
            *(const __hip_bfloat162*)(ht_bf + (size_t)ceA.x * HF + 2 * lane));
        acc0.x = fmaf(exA, hvA.x, acc0.x); acc0.y = fmaf(exA, hvA.y, acc0.y);
        den0 += exA;
    }
    float den = den0 + den1;
    float rden = 1.0f / (den + 1e-8f);
    float ox = (acc0.x + acc1.x) * rden, oy = (acc0.y + acc1.y) * rden;
    ox = ox > 0.f ? ox : expm1f(ox);               // fused ELU
    oy = oy > 0.f ? oy : expm1f(oy);
    float2 o = {ox, oy};
    ((float2*)(hout + (size_t)n * HF))[lane] = o;
    // normalize att: 16 edges/iter; exs read coalesced, att write scattered
    int h = lane & 3;
    float rden_h = __shfl(rden, h * 16, 64);       // lane h*16 holds head-h rden
    for (int p0 = beg; p0 < end; p0 += 16) {
        int q = p0 + (lane >> 2);
        if (q < end) {
            int eid = csr[q].y;
            float ex = exs[(size_t)q * 4 + h];
            att[(size_t)eid * 4 + h] = ex * rden_h;
        }
    }
}

extern "C" void kernel_launch(void* const* d_in, const int* in_sizes, int n_in,
                              void* d_out, int out_size, void* d_ws, size_t ws_size,
                              hipStream_t stream) {
    const float* h  = (const float*)d_in[0];
    const int*   ei = (const int*)  d_in[1];
    const float* ea = (const float*)d_in[2];
    const float* W  = (const float*)d_in[3];
    const float* a  = (const float*)d_in[4];
    const float* eW = (const float*)d_in[5];
    const float* eb = (const float*)d_in[6];

    float* out  = (float*)d_out;
    float* hout = out;                                   // 50000*128
    float* att  = out + (size_t)N_NODES * HF;            // 800000*4 (final normalized)

    char* wsb = (char*)d_ws;
    __hip_bfloat16* ht_bf = (__hip_bfloat16*)wsb;        // 6.4M bf16 = 12.8 MB
    float* alpha_i = (float*)(wsb + (size_t)N_NODES * HF * 2);  // 200,000 f
    float* alpha_j = alpha_i + N_NODES * HEADS;          // 200,000 f
    float* w_eff   = alpha_j + N_NODES * HEADS;          // 128 f
    float* b_eff   = w_eff + 128;                        // 4 f
    int*   deg     = (int*)(b_eff + 4);                  // 50,000 i
    int*   row_off = deg + N_NODES;                      // 50,001 i
    int*   cursor  = row_off + N_NODES + 1;              // 50,000 i
    int*   blk_sums= cursor + N_NODES;                   // 196 i
    int*   blk_off = blk_sums + NBLK;                    // 196 i
    int2*  csr     = (int2*)((((uintptr_t)(blk_off + NBLK)) + 15) & ~(uintptr_t)15);
    float* exs     = (float*)(csr + N_EDGES);            // 3,200,000 f

    const int* row = ei;
    const int* col = ei + N_EDGES;

    hipMemsetAsync(deg, 0, (size_t)N_NODES * sizeof(int), stream);

    prep_kernel<<<1, 160, 0, stream>>>(eW, eb, a, w_eff, b_eff);
    node_kernel<<<N_NODES / NB, 256, 0, stream>>>(h, W, a, ht_bf, alpha_i, alpha_j);
    count_kernel<<<(N_EDGES / 4 + 255) / 256, 256, 0, stream>>>(row, deg);
    scan1_kernel<<<NBLK, SB, 0, stream>>>(deg, row_off, blk_sums);
    scan2_kernel<<<1, SB, 0, stream>>>(blk_sums, blk_off, row_off);
    scan3_kernel<<<NBLK, SB, 0, stream>>>(blk_off, row_off, cursor);
    edge_kernel<<<N_EDGES / EB, 256, 0, stream>>>(row, col, ea, w_eff, b_eff,
                                                  alpha_i, alpha_j,
                                                  cursor, csr, exs);
    agg_kernel<<<(N_NODES + 3) / 4, 256, 0, stream>>>(row_off, csr, exs,
                                                      ht_bf, hout, att);
}

// Round 6
// 383.621 us; speedup vs baseline: 4.2180x; 1.0158x over previous
//
#include <hip/hip_runtime.h>
#include <hip/hip_bf16.h>

#define N_NODES 50000
#define N_EDGES 800000
#define IN_F 128
#define OUT_F 32
#define HEADS 4
#define EDGE_F 32
#define HF 128          // HEADS*OUT_F
#define NB 16           // nodes per block in node_kernel (50000 = 3125*16 exact)
#define EB 64           // edges per block in edge_kernel
#define SB 256          // scan block size
#define NBLK ((N_NODES + SB - 1) / SB)   // 196 scan blocks

// CSR record, 32 B: [ex0 ex1 ex2 ex3 | col eid | pad pad]
// One scattered 64B-line touch per edge instead of two (R5: separate exs+csr).

// ---- fold eW/eb/a_e into w_eff[32x4], b_eff[4] --------------------------
__global__ void prep_kernel(const float* __restrict__ eW, const float* __restrict__ eb,
                            const float* __restrict__ a,
                            float* __restrict__ w_eff, float* __restrict__ b_eff) {
    int t = threadIdx.x;
    if (t < 128) {
        int k = t >> 2, h = t & 3;
        float s = 0.f;
        #pragma unroll
        for (int f = 0; f < EDGE_F; ++f)
            s = fmaf(eW[k * HF + h * OUT_F + f], a[h * 96 + 2 * OUT_F + f], s);
        w_eff[k * 4 + h] = s;
    } else if (t < 132) {
        int h = t - 128;
        float s = 0.f;
        #pragma unroll
        for (int f = 0; f < EDGE_F; ++f)
            s = fmaf(eb[h * OUT_F + f], a[h * 96 + 2 * OUT_F + f], s);
        b_eff[h] = s;
    }
}

// ---- ht = h @ W (fp32 math, bf16 out), alpha_i/alpha_j per node ---------
__global__ __launch_bounds__(256) void node_kernel(
        const float* __restrict__ h, const float* __restrict__ W,
        const float* __restrict__ a,
        __hip_bfloat16* __restrict__ ht_bf,
        float* __restrict__ alpha_i, float* __restrict__ alpha_j) {
    int tid = threadIdx.x;
    int g = tid >> 6, lane = tid & 63;
    int n0 = blockIdx.x * NB;
    __shared__ __align__(16) float hs[NB][IN_F];
    {   // cooperative float4 load of 16 node rows (2048 floats)
        const float4* src = (const float4*)(h + (size_t)n0 * IN_F);
        float4* dst = (float4*)(&hs[0][0]);
        dst[tid] = src[tid];
        dst[tid + 256] = src[tid + 256];
    }
    __syncthreads();
    float acc0[4] = {0.f, 0.f, 0.f, 0.f};
    float acc1[4] = {0.f, 0.f, 0.f, 0.f};
    const float2* Wv = (const float2*)W;       // row k: float2 idx k*64 + lane
    #pragma unroll 8
    for (int k4 = 0; k4 < IN_F / 4; ++k4) {
        float4 hv[4];
        #pragma unroll
        for (int i = 0; i < 4; ++i)
            hv[i] = *(const float4*)&hs[g * 4 + i][k4 * 4];
        #pragma unroll
        for (int kk = 0; kk < 4; ++kk) {
            float2 w = Wv[(k4 * 4 + kk) * 64 + lane];
            #pragma unroll
            for (int i = 0; i < 4; ++i) {
                float hvv = (&hv[i].x)[kk];
                acc0[i] = fmaf(hvv, w.x, acc0[i]);
                acc1[i] = fmaf(hvv, w.y, acc1[i]);
            }
        }
    }
    int hh = lane >> 4;                        // head of cols 2L,2L+1
    int f0 = (2 * lane) & 31;
    float ai0 = a[hh * 96 + f0],      ai1 = a[hh * 96 + f0 + 1];
    float aj0 = a[hh * 96 + 32 + f0], aj1 = a[hh * 96 + 32 + f0 + 1];
    #pragma unroll
    for (int i = 0; i < 4; ++i) {
        int n = n0 + g * 4 + i;
        *(__hip_bfloat162*)(ht_bf + (size_t)n * HF + 2 * lane) =
            __float22bfloat162_rn(make_float2(acc0[i], acc1[i]));
        float pi = fmaf(acc0[i], ai0, acc1[i] * ai1);
        float pj = fmaf(acc0[i], aj0, acc1[i] * aj1);
        #pragma unroll
        for (int s = 8; s > 0; s >>= 1) {      // reduce within 16-lane head segment
            pi += __shfl_down(pi, s, 16);
            pj += __shfl_down(pj, s, 16);
        }
        if ((lane & 15) == 0) {
            alpha_i[n * 4 + hh] = pi;
            alpha_j[n * 4 + hh] = pj;
        }
    }
}

// ---- CSR build: degree histogram (int4 loads) ---------------------------
__global__ __launch_bounds__(256) void count_kernel(const int* __restrict__ row,
                                                    int* __restrict__ deg) {
    int t = blockIdx.x * 256 + threadIdx.x;        // over N_EDGES/4 = 200000
    if (t < N_EDGES / 4) {
        int4 r4 = ((const int4*)row)[t];
        atomicAdd(&deg[r4.x], 1);
        atomicAdd(&deg[r4.y], 1);
        atomicAdd(&deg[r4.z], 1);
        atomicAdd(&deg[r4.w], 1);
    }
}

// ---- hierarchical exclusive scan ----------------------------------------
__device__ __forceinline__ int block_incl_scan(int v, int lane, int wid, int* wsum) {
    int x = v;
    #pragma unroll
    for (int s = 1; s < 64; s <<= 1) {
        int y = __shfl_up(x, s, 64);
        if (lane >= s) x += y;
    }
    if (lane == 63) wsum[wid] = x;
    __syncthreads();
    int add = 0;
    #pragma unroll
    for (int w = 0; w < 4; ++w) add += (w < wid) ? wsum[w] : 0;
    return x + add;            // block-level inclusive scan of v
}

__global__ __launch_bounds__(SB) void scan1_kernel(const int* __restrict__ deg,
                                                   int* __restrict__ row_off,
                                                   int* __restrict__ blk_sums) {
    __shared__ int wsum[4];
    int i = blockIdx.x * SB + threadIdx.x;
    int v = (i < N_NODES) ? deg[i] : 0;
    int incl = block_incl_scan(v, threadIdx.x & 63, threadIdx.x >> 6, wsum);
    if (i < N_NODES) row_off[i] = incl - v;              // local exclusive
    if (threadIdx.x == SB - 1) blk_sums[blockIdx.x] = incl;
}

__global__ __launch_bounds__(SB) void scan2_kernel(int* __restrict__ blk_sums,
                                                   int* __restrict__ blk_off,
                                                   int* __restrict__ row_off) {
    __shared__ int wsum[4];
    int t = threadIdx.x;
    int v = (t < NBLK) ? blk_sums[t] : 0;
    int incl = block_incl_scan(v, t & 63, t >> 6, wsum);
    if (t < NBLK) blk_off[t] = incl - v;                 // exclusive block offset
    if (t == SB - 1) row_off[N_NODES] = incl;            // grand total (== N_EDGES)
}

__global__ __launch_bounds__(SB) void scan3_kernel(const int* __restrict__ blk_off,
                                                   int* __restrict__ row_off,
                                                   int* __restrict__ cursor) {
    int i = blockIdx.x * SB + threadIdx.x;
    if (i < N_NODES) {
        int v = row_off[i] + blk_off[blockIdx.x];
        row_off[i] = v;
        cursor[i] = v;
    }
}

// ---- edge logits -> exp scattered into 32B CSR records ------------------
__global__ __launch_bounds__(256) void edge_kernel(
        const int* __restrict__ row, const int* __restrict__ col,
        const float* __restrict__ ea,
        const float* __restrict__ w_eff, const float* __restrict__ b_eff,
        const float* __restrict__ alpha_i, const float* __restrict__ alpha_j,
        int* __restrict__ cursor, float* __restrict__ rec) {
    __shared__ __align__(16) float eas[EB][EDGE_F + 4];
    __shared__ float wsd[128];
    __shared__ float bs[4];
    int t = threadIdx.x;
    int e0 = blockIdx.x * EB;
    if (t < 128) wsd[t] = w_eff[t];
    if (t < 4) bs[t] = b_eff[t];
    {   // stage EB edge rows (2048 floats) as float4
        const float4* src = (const float4*)(ea + (size_t)e0 * EDGE_F);
        #pragma unroll
        for (int u = 0; u < 2; ++u) {
            int idx = t + u * 256;
            int i = idx >> 3, f4 = idx & 7;
            ((float4*)&eas[i][0])[f4] = src[idx];
        }
    }
    __syncthreads();
    int i = t >> 2, hh = t & 3;
    int e = e0 + i;
    float s = bs[hh];
    #pragma unroll
    for (int k = 0; k < EDGE_F; ++k) s = fmaf(eas[i][k], wsd[k * 4 + hh], s);
    int r = row[e], c = col[e];
    float ev = s + alpha_i[r * 4 + hh] + alpha_j[c * 4 + hh];
    ev = ev > 0.f ? ev : 0.2f * ev;               // leaky_relu(0.2)
    float ex = __expf(ev);                        // no max-shift: |e| small, fp32-safe
    int pos = 0;
    if (hh == 0) pos = atomicAdd(&cursor[r], 1);
    pos = __shfl(pos, (t & 63) & ~3, 64);         // broadcast within the 4-lane group
    rec[(size_t)pos * 8 + hh] = ex;               // ex[4]: 16B contiguous
    if (hh == 0)
        *(int2*)(rec + (size_t)pos * 8 + 4) = make_int2(c, e);  // same 32B record
}

// ---- per-node aggregation: one wave per node ----------------------------
// h_out[n] = elu( (sum ex * ht_bf[col]) / (den+1e-8) ); att[eid] = ex/den
__global__ __launch_bounds__(256) void agg_kernel(
        const int* __restrict__ row_off, const float* __restrict__ rec,
        const __hip_bfloat16* __restrict__ ht_bf,
        float* __restrict__ hout, float* __restrict__ att) {
    int wave = threadIdx.x >> 6;
    int lane = threadIdx.x & 63;
    int n = blockIdx.x * 4 + wave;
    if (n >= N_NODES) return;
    int beg = row_off[n], end = row_off[n + 1];
    int h2 = lane >> 4;                            // head of cols 2L,2L+1
    float2 acc0 = {0.f, 0.f}, acc1 = {0.f, 0.f};
    float den0 = 0.f, den1 = 0.f;
    int p = beg;
    for (; p + 1 < end; p += 2) {                  // unroll x2 for load ILP
        const float* rA = rec + (size_t)p * 8;
        const float* rB = rA + 8;
        float exA = rA[h2];
        float exB = rB[h2];
        int cA = *(const int*)(rA + 4);
        int cB = *(const int*)(rB + 4);
        float2 hvA = __bfloat1622float2(
            *(const __hip_bfloat162*)(ht_bf + (size_t)cA * HF + 2 * lane));
        float2 hvB = __bfloat1622float2(
            *(const __hip_bfloat162*)(ht_bf + (size_t)cB * HF + 2 * lane));
        acc0.x = fmaf(exA, hvA.x, acc0.x); acc0.y = fmaf(exA, hvA.y, acc0.y);
        acc1.x = fmaf(exB, hvB.x, acc1.x); acc1.y = fmaf(exB, hvB.y, acc1.y);
        den0 += exA; den1 += exB;
    }
    if (p < end) {
        const float* rA = rec + (size_t)p * 8;
        float exA = rA[h2];
        int cA = *(const int*)(rA + 4);
        float2 hvA = __bfloat1622float2(
            *(const __hip_bfloat162*)(ht_bf + (size_t)cA * HF + 2 * lane));
        acc0.x = fmaf(exA, hvA.x, acc0.x); acc0.y = fmaf(exA, hvA.y, acc0.y);
        den0 += exA;
    }
    float den = den0 + den1;
    float rden = 1.0f / (den + 1e-8f);
    float ox = (acc0.x + acc1.x) * rden, oy = (acc0.y + acc1.y) * rden;
    ox = ox > 0.f ? ox : expm1f(ox);               // fused ELU
    oy = oy > 0.f ? oy : expm1f(oy);
    float2 o = {ox, oy};
    ((float2*)(hout + (size_t)n * HF))[lane] = o;
    // normalize att: 16 edges/iter; rec read sequential, att write scattered
    int h = lane & 3;
    float rden_h = __shfl(rden, h * 16, 64);       // lane h*16 holds head-h rden
    for (int p0 = beg; p0 < end; p0 += 16) {
        int q = p0 + (lane >> 2);
        if (q < end) {
            const float* rQ = rec + (size_t)q * 8;
            int eid = *(const int*)(rQ + 5);
            float ex = rQ[h];
            att[(size_t)eid * 4 + h] = ex * rden_h;
        }
    }
}

extern "C" void kernel_launch(void* const* d_in, const int* in_sizes, int n_in,
                              void* d_out, int out_size, void* d_ws, size_t ws_size,
                              hipStream_t stream) {
    const float* h  = (const float*)d_in[0];
    const int*   ei = (const int*)  d_in[1];
    const float* ea = (const float*)d_in[2];
    const float* W  = (const float*)d_in[3];
    const float* a  = (const float*)d_in[4];
    const float* eW = (const float*)d_in[5];
    const float* eb = (const float*)d_in[6];

    float* out  = (float*)d_out;
    float* hout = out;                                   // 50000*128
    float* att  = out + (size_t)N_NODES * HF;            // 800000*4 (final normalized)

    char* wsb = (char*)d_ws;
    __hip_bfloat16* ht_bf = (__hip_bfloat16*)wsb;        // 6.4M bf16 = 12.8 MB
    float* alpha_i = (float*)(wsb + (size_t)N_NODES * HF * 2);  // 200,000 f
    float* alpha_j = alpha_i + N_NODES * HEADS;          // 200,000 f
    float* w_eff   = alpha_j + N_NODES * HEADS;          // 128 f
    float* b_eff   = w_eff + 128;                        // 4 f
    int*   deg     = (int*)(b_eff + 4);                  // 50,000 i
    int*   row_off = deg + N_NODES;                      // 50,001 i
    int*   cursor  = row_off + N_NODES + 1;              // 50,000 i
    int*   blk_sums= cursor + N_NODES;                   // 196 i
    int*   blk_off = blk_sums + NBLK;                    // 196 i
    float* rec     = (float*)((((uintptr_t)(blk_off + NBLK)) + 31) & ~(uintptr_t)31);
    // rec: 800,000 * 32 B = 25.6 MB

    const int* row = ei;
    const int* col = ei + N_EDGES;

    hipMemsetAsync(deg, 0, (size_t)N_NODES * sizeof(int), stream);

    prep_kernel<<<1, 160, 0, stream>>>(eW, eb, a, w_eff, b_eff);
    node_kernel<<<N_NODES / NB, 256, 0, stream>>>(h, W, a, ht_bf, alpha_i, alpha_j);
    count_kernel<<<(N_EDGES / 4 + 255) / 256, 256, 0, stream>>>(row, deg);
    scan1_kernel<<<NBLK, SB, 0, stream>>>(deg, row_off, blk_sums);
    scan2_kernel<<<1, SB, 0, stream>>>(blk_sums, blk_off, row_off);
    scan3_kernel<<<NBLK, SB, 0, stream>>>(blk_off, row_off, cursor);
    edge_kernel<<<N_EDGES / EB, 256, 0, stream>>>(row, col, ea, w_eff, b_eff,
                                                  alpha_i, alpha_j, cursor, rec);
    agg_kernel<<<(N_NODES + 3) / 4, 256, 0, stream>>>(row_off, rec, ht_bf, hout, att);
}